// Round 1
// baseline (6764.018 us; speedup 1.0000x reference)
//
#include <hip/hip_runtime.h>

#define NSAMP 32768
#define XDIM 8
#define LSTEPS 16
#define DDIM 64
#define RDIM 64
#define HIDE 256
#define HIDN 512
#define MIXN 32

// ws layout (float offsets)
#define OFF_W1N 0        // 8 chunks [64k][64o]  (nade_w1 512x64 -> k=i)
#define OFF_W2N 32768    // [512k][64o]          (nade_w2 64x512 -> k=e)
#define OFF_MU  65536    // 4 chunks [64k][64o]  (mu_w 256x64 -> k=r)
#define OFF_SIG 81920    // 4 chunks
#define OFF_ALP 98304    // [64k][64o] rows o>=32 zero (alpha_w 32x64)
#define OFF_W1E 102400   // 4 chunks [8k][64o]   (enc1_w 256x8)
#define OFF_W2E 104448   // [256k][64o]          (enc2_w 64x256 -> k=e)
#define WS_FLOATS 120832

#define HALF_LOG2PI 0.91893853320467274f

__global__ void prep_kernel(const float* __restrict__ nw1, const float* __restrict__ nw2,
                            const float* __restrict__ muw, const float* __restrict__ sgw,
                            const float* __restrict__ alw, const float* __restrict__ e1w,
                            const float* __restrict__ e2w, float* __restrict__ ws,
                            float* __restrict__ out) {
  int idx = blockIdx.x * blockDim.x + threadIdx.x;
  int stride = gridDim.x * blockDim.x;
  for (int i = idx; i < WS_FLOATS; i += stride) {
    float v;
    if (i < OFF_W2N) {
      int oc = i >> 12, r = i & 4095, k = r >> 6, o = r & 63;
      v = nw1[(oc * 64 + o) * RDIM + k];
    } else if (i < OFF_MU) {
      int j = i - OFF_W2N; int k = j >> 6, o = j & 63;
      v = nw2[o * HIDN + k];
    } else if (i < OFF_SIG) {
      int j = i - OFF_MU; int oc = j >> 12, r = j & 4095, k = r >> 6, o = r & 63;
      v = muw[(oc * 64 + o) * RDIM + k];
    } else if (i < OFF_ALP) {
      int j = i - OFF_SIG; int oc = j >> 12, r = j & 4095, k = r >> 6, o = r & 63;
      v = sgw[(oc * 64 + o) * RDIM + k];
    } else if (i < OFF_W1E) {
      int j = i - OFF_ALP; int k = j >> 6, o = j & 63;
      v = (o < MIXN) ? alw[o * RDIM + k] : 0.0f;
    } else if (i < OFF_W2E) {
      int j = i - OFF_W1E; int oc = j >> 9, r = j & 511, k = r >> 6, o = r & 63;
      v = e1w[(oc * 64 + o) * XDIM + k];
    } else {
      int j = i - OFF_W2E; int k = j >> 6, o = j & 63;
      v = e2w[o * HIDE + k];
    }
    ws[i] = v;
  }
  if (idx == 0) out[NSAMP] = 0.0f;
}

// acc[oi][si] += sum_k Wg[k][og4+oi] * AT[k][sg4+si]   (AT: LDS [64k][64s], Wg: global [64k][64o])
__device__ __forceinline__ void gemm_acc64(const float* __restrict__ AT,
                                           const float* __restrict__ Wg,
                                           float acc[4][4], int sg4, int og4) {
#pragma unroll 4
  for (int k = 0; k < 64; ++k) {
    float4 a = *reinterpret_cast<const float4*>(AT + k * 64 + sg4);
    float4 w = *reinterpret_cast<const float4*>(Wg + k * 64 + og4);
    const float av[4] = {a.x, a.y, a.z, a.w};
    const float wv[4] = {w.x, w.y, w.z, w.w};
#pragma unroll
    for (int oi = 0; oi < 4; ++oi)
#pragma unroll
      for (int si = 0; si < 4; ++si)
        acc[oi][si] = fmaf(wv[oi], av[si], acc[oi][si]);
  }
}

__device__ __forceinline__ void gemm_acc8(const float* __restrict__ AT,
                                          const float* __restrict__ Wg,
                                          float acc[4][4], int sg4, int og4) {
#pragma unroll
  for (int k = 0; k < 8; ++k) {
    float4 a = *reinterpret_cast<const float4*>(AT + k * 64 + sg4);
    float4 w = *reinterpret_cast<const float4*>(Wg + k * 64 + og4);
    const float av[4] = {a.x, a.y, a.z, a.w};
    const float wv[4] = {w.x, w.y, w.z, w.w};
#pragma unroll
    for (int oi = 0; oi < 4; ++oi)
#pragma unroll
      for (int si = 0; si < 4; ++si)
        acc[oi][si] = fmaf(wv[oi], av[si], acc[oi][si]);
  }
}

__device__ __forceinline__ void epi_store(float* __restrict__ OT, const float* __restrict__ bias,
                                          float acc[4][4], int sg4, int og4, bool relu) {
  float4 b = *reinterpret_cast<const float4*>(bias + og4);
  const float bv[4] = {b.x, b.y, b.z, b.w};
#pragma unroll
  for (int oi = 0; oi < 4; ++oi) {
    float4 o4;
    float v0 = acc[oi][0] + bv[oi], v1 = acc[oi][1] + bv[oi];
    float v2 = acc[oi][2] + bv[oi], v3 = acc[oi][3] + bv[oi];
    if (relu) { v0 = fmaxf(v0, 0.f); v1 = fmaxf(v1, 0.f); v2 = fmaxf(v2, 0.f); v3 = fmaxf(v3, 0.f); }
    o4.x = v0; o4.y = v1; o4.z = v2; o4.w = v3;
    *reinterpret_cast<float4*>(OT + (og4 + oi) * 64 + sg4) = o4;
  }
}

__global__ __launch_bounds__(256, 2)
void fused_kernel(const float* __restrict__ X, const float* __restrict__ init_w,
                  const float* __restrict__ cores,
                  const float* __restrict__ b1e, const float* __restrict__ b2e,
                  const float* __restrict__ b1n, const float* __restrict__ b2n,
                  const float* __restrict__ mub, const float* __restrict__ sgb,
                  const float* __restrict__ alb,
                  const float* __restrict__ ws, float* __restrict__ out) {
  __shared__ __align__(16) float tmpA[4096];
  __shared__ __align__(16) float tmpB[4096];
  __shared__ __align__(16) float ENC[4096];  // also: clp = ENC[0..2047]
  __shared__ __align__(16) float G1[4096];   // h1c / hec / lsc / alpha(32x64) / reduce
  __shared__ __align__(16) float H2[4096];

  const int tid = threadIdx.x;
  const int sg4 = (tid & 15) * 4;
  const int og4 = (tid >> 4) * 4;
  const int n0 = blockIdx.x * 64;

  float res_reg = 0.f, norm_reg = 0.f;

  // tmp0: tmpT[i][s] = init_w[i]
  for (int i = tid; i < 4096; i += 256) tmpA[i] = init_w[i >> 6];

  for (int t = 0; t < LSTEPS; ++t) {
    float* tc = (t & 1) ? tmpB : tmpA;
    float* tn = (t & 1) ? tmpA : tmpB;
    float* XT = tn;        // overlay: x_t tile [8][64] in the dead next-buffer
    float* clp = ENC;      // overlay: comp_lp [32][64]

    for (int i = tid; i < 512; i += 256) {
      int d = i >> 6, s = i & 63;
      XT[i] = X[(size_t)(n0 + s) * (XDIM * LSTEPS) + d * LSTEPS + t];
    }
    for (int i = tid; i < 2048; i += 256) clp[i] = 0.f;
    __syncthreads();

    // norm accumulation for tmp_t
#pragma unroll
    for (int q = 0; q < 16; ++q) { float v = tc[tid * 16 + q]; norm_reg += v * v; }

    // ---- phi: h1 (512) -> h2 (64), fused chunked over e ----
    float acc2[4][4] = {};
    for (int oc = 0; oc < 8; ++oc) {
      float acc1[4][4] = {};
      gemm_acc64(tc, ws + OFF_W1N + oc * 4096, acc1, sg4, og4);
      epi_store(G1, b1n + oc * 64, acc1, sg4, og4, true);
      __syncthreads();
      gemm_acc64(G1, ws + OFF_W2N + oc * 4096, acc2, sg4, og4);
      __syncthreads();
    }
    {
      float4 b = *reinterpret_cast<const float4*>(b2n + og4);
      const float bv[4] = {b.x, b.y, b.z, b.w};
#pragma unroll
      for (int oi = 0; oi < 4; ++oi) {
        float4 o4;
        o4.x = fmaxf(acc2[oi][0] + bv[oi], 0.f);
        o4.y = fmaxf(acc2[oi][1] + bv[oi], 0.f);
        o4.z = fmaxf(acc2[oi][2] + bv[oi], 0.f);
        o4.w = fmaxf(acc2[oi][3] + bv[oi], 0.f);
        *reinterpret_cast<float4*>(H2 + (og4 + oi) * 64 + sg4) = o4;
      }
    }
    __syncthreads();

    // ---- mixture density: per 64-row block of mu/sig ----
    for (int ob = 0; ob < 4; ++ob) {
      float accS[4][4] = {};
      gemm_acc64(H2, ws + OFF_SIG + ob * 4096, accS, sg4, og4);
      epi_store(G1, sgb + ob * 64, accS, sg4, og4, false);  // lsc
      __syncthreads();
      float accM[4][4] = {};
      gemm_acc64(H2, ws + OFF_MU + ob * 4096, accM, sg4, og4);
      {
        float4 bm = *reinterpret_cast<const float4*>(mub + ob * 64 + og4);
        const float bmv[4] = {bm.x, bm.y, bm.z, bm.w};
        float part[4] = {0.f, 0.f, 0.f, 0.f};
#pragma unroll
        for (int oi = 0; oi < 4; ++oi) {
          int d = (og4 + oi) & 7;
#pragma unroll
          for (int si = 0; si < 4; ++si) {
            float mu = accM[oi][si] + bmv[oi];
            float ls = G1[(og4 + oi) * 64 + sg4 + si];
            float xv = XT[d * 64 + sg4 + si];
            float z = (xv - mu) * __expf(-ls);
            part[si] += -0.5f * z * z - ls - HALF_LOG2PI;
          }
        }
        int m = (ob * 64 + og4) >> 3;
#pragma unroll
        for (int si = 0; si < 4; ++si) atomicAdd(&clp[m * 64 + sg4 + si], part[si]);
      }
      __syncthreads();
    }

    // ---- alpha logits ----
    {
      float accA[4][4] = {};
      gemm_acc64(H2, ws + OFF_ALP, accA, sg4, og4);
      if (og4 < 32) {
        float4 b = *reinterpret_cast<const float4*>(alb + og4);
        const float bv[4] = {b.x, b.y, b.z, b.w};
#pragma unroll
        for (int oi = 0; oi < 4; ++oi) {
          float4 o4;
          o4.x = accA[oi][0] + bv[oi]; o4.y = accA[oi][1] + bv[oi];
          o4.z = accA[oi][2] + bv[oi]; o4.w = accA[oi][3] + bv[oi];
          *reinterpret_cast<float4*>(G1 + (og4 + oi) * 64 + sg4) = o4;
        }
      }
    }
    __syncthreads();

    // ---- logsumexp(alpha+clp) - logsumexp(alpha) ----
    if (tid < 64) {
      int s = tid;
      float m1 = -1e30f, m2 = -1e30f;
      for (int m = 0; m < 32; ++m) {
        float a = G1[m * 64 + s], c = clp[m * 64 + s];
        m1 = fmaxf(m1, a + c); m2 = fmaxf(m2, a);
      }
      float s1 = 0.f, s2 = 0.f;
      for (int m = 0; m < 32; ++m) {
        float a = G1[m * 64 + s], c = clp[m * 64 + s];
        s1 += __expf(a + c - m1); s2 += __expf(a - m2);
      }
      res_reg += (m1 + __logf(s1)) - (m2 + __logf(s2));
    }
    __syncthreads();

    if (t == LSTEPS - 1) break;

    // ---- encoder: enc_t = (relu(x W1e^T + b1e)) W2e^T + b2e ----
    float accE[4][4] = {};
    for (int oc = 0; oc < 4; ++oc) {
      float acc1[4][4] = {};
      gemm_acc8(XT, ws + OFF_W1E + oc * 512, acc1, sg4, og4);
      epi_store(G1, b1e + oc * 64, acc1, sg4, og4, true);
      __syncthreads();
      gemm_acc64(G1, ws + OFF_W2E + oc * 4096, accE, sg4, og4);
      __syncthreads();
    }
    {
      float4 b = *reinterpret_cast<const float4*>(b2e + og4);
      const float bv[4] = {b.x, b.y, b.z, b.w};
#pragma unroll
      for (int oi = 0; oi < 4; ++oi) {
        float4 o4;
        o4.x = accE[oi][0] + bv[oi]; o4.y = accE[oi][1] + bv[oi];
        o4.z = accE[oi][2] + bv[oi]; o4.w = accE[oi][3] + bv[oi];
        *reinterpret_cast<float4*>(ENC + (og4 + oi) * 64 + sg4) = o4;
      }
    }
    __syncthreads();

    // ---- tmp update: tmp_new[j][s] = sum_i sum_d core[i][d][j] * tmp[i][s] * enc[d][s] ----
    {
      float accU[4][4] = {};
      const float* cg = cores + (size_t)t * (RDIM * DDIM * RDIM);
      for (int i = 0; i < 64; ++i) {
        float4 t4 = *reinterpret_cast<const float4*>(tc + i * 64 + sg4);
        const float tv[4] = {t4.x, t4.y, t4.z, t4.w};
        const float* cgi = cg + i * 4096;
#pragma unroll 4
        for (int k = 0; k < 64; ++k) {
          float4 e = *reinterpret_cast<const float4*>(ENC + k * 64 + sg4);
          float4 w = *reinterpret_cast<const float4*>(cgi + k * 64 + og4);
          const float av[4] = {tv[0] * e.x, tv[1] * e.y, tv[2] * e.z, tv[3] * e.w};
          const float wv[4] = {w.x, w.y, w.z, w.w};
#pragma unroll
          for (int oi = 0; oi < 4; ++oi)
#pragma unroll
            for (int si = 0; si < 4; ++si)
              accU[oi][si] = fmaf(wv[oi], av[si], accU[oi][si]);
        }
      }
#pragma unroll
      for (int oi = 0; oi < 4; ++oi) {
        float4 o4;
        o4.x = accU[oi][0]; o4.y = accU[oi][1]; o4.z = accU[oi][2]; o4.w = accU[oi][3];
        *reinterpret_cast<float4*>(tn + (og4 + oi) * 64 + sg4) = o4;
      }
    }
    __syncthreads();
  }

  if (tid < 64) out[n0 + tid] = res_reg;

  // norm reduction
  __syncthreads();
  G1[tid] = norm_reg;
  __syncthreads();
  if (tid < 64) {
    float v = G1[tid] + G1[tid + 64] + G1[tid + 128] + G1[tid + 192];
    for (int off = 32; off > 0; off >>= 1) v += __shfl_down(v, off);
    if (tid == 0) atomicAdd(out + NSAMP, v);
  }
}

extern "C" void kernel_launch(void* const* d_in, const int* in_sizes, int n_in,
                              void* d_out, int out_size, void* d_ws, size_t ws_size,
                              hipStream_t stream) {
  const float* X      = (const float*)d_in[0];
  const float* init_w = (const float*)d_in[1];
  const float* cores  = (const float*)d_in[2];
  const float* e1w    = (const float*)d_in[3];
  const float* b1e    = (const float*)d_in[4];
  const float* e2w    = (const float*)d_in[5];
  const float* b2e    = (const float*)d_in[6];
  const float* nw1    = (const float*)d_in[7];
  const float* b1n    = (const float*)d_in[8];
  const float* nw2    = (const float*)d_in[9];
  const float* b2n    = (const float*)d_in[10];
  const float* muw    = (const float*)d_in[11];
  const float* mub    = (const float*)d_in[12];
  const float* sgw    = (const float*)d_in[13];
  const float* sgb    = (const float*)d_in[14];
  const float* alw    = (const float*)d_in[15];
  const float* alb    = (const float*)d_in[16];
  float* out = (float*)d_out;
  float* ws  = (float*)d_ws;

  prep_kernel<<<64, 256, 0, stream>>>(nw1, nw2, muw, sgw, alw, e1w, e2w, ws, out);
  fused_kernel<<<NSAMP / 64, 256, 0, stream>>>(X, init_w, cores, b1e, b2e, b1n, b2n,
                                               mub, sgb, alb, ws, out);
}

// Round 2
// 971.483 us; speedup vs baseline: 6.9626x; 6.9626x over previous
//
#include <hip/hip_runtime.h>

typedef unsigned short u16;
typedef unsigned int u32;
typedef __attribute__((ext_vector_type(8))) __bf16 bf16x8;
typedef __attribute__((ext_vector_type(4))) float f32x4;

#define NSAMP 32768
#define HALF_LOG2PI 0.91893853320467274f

// ws element offsets (u16 units)
#define O_W1N 0
#define O_W2N 32768
#define O_MUW 65536
#define O_SGW 81920
#define O_ALW 98304
#define O_E1W 100352
#define O_E2W 108544
#define O_CORT 124928
#define CORT_STEP 262144
#define WS_U16 4057088

// LDS byte offsets (total 67648, 2 blocks/CU)
#define LH1A 0
#define LH1B 8192
#define LCLP 0
#define LALP 8192
#define LH2  16384
#define LXP  24576
#define LENC 32768
#define LTMPA 49152
#define LTMPB 57344
#define LXT  65536
#define XTS 66
#define LDS_BYTES 67648

static __device__ __forceinline__ u16 f2b(float x){ return __builtin_bit_cast(u16,(__bf16)x); }
static __device__ __forceinline__ float b2f(u16 u){ return __builtin_bit_cast(float,((u32)u)<<16); }
static __device__ __forceinline__ u32 pk2(float lo, float hi){
  return (u32)__builtin_bit_cast(u16,(__bf16)lo) | ((u32)__builtin_bit_cast(u16,(__bf16)hi)<<16);
}
static __device__ __forceinline__ f32x4 MF(uint4 a, uint4 b, f32x4 c){
  union U{uint4 q; bf16x8 v;};
  U A, B; A.q=a; B.q=b;
  return __builtin_amdgcn_mfma_f32_16x16x32_bf16(A.v, B.v, c, 0, 0, 0);
}

// ---------------- prep: weights -> bf16 (k-contiguous rows kept) ----------------
__global__ void prep_w(const float* __restrict__ nw1, const float* __restrict__ nw2,
                       const float* __restrict__ muw, const float* __restrict__ sgw,
                       const float* __restrict__ alw, const float* __restrict__ e1w,
                       const float* __restrict__ e2w, u16* __restrict__ ws,
                       float* __restrict__ out) {
  int idx0 = blockIdx.x * blockDim.x + threadIdx.x;
  int stride = gridDim.x * blockDim.x;
  for (int idx = idx0; idx < 124928; idx += stride) {
    float v;
    if      (idx < 32768)  v = nw1[idx];
    else if (idx < 65536)  v = nw2[idx - 32768];
    else if (idx < 81920)  v = muw[idx - 65536];
    else if (idx < 98304)  v = sgw[idx - 81920];
    else if (idx < 100352) v = alw[idx - 98304];
    else if (idx < 108544) { int j = idx - 100352; int o = j >> 5, k = j & 31;
                             v = (k < 8) ? e1w[o*8 + k] : 0.0f; }
    else                   v = e2w[idx - 108544];
    ws[idx] = f2b(v);
  }
  if (idx0 == 0) out[NSAMP] = 0.0f;
}

// ---------------- prep: cores[t][i][d][j] -> coreT[t][j][i*64+d] bf16 ----------------
__global__ void prep_core(const float* __restrict__ cores, u16* __restrict__ ws) {
  int t = blockIdx.x >> 6, i = blockIdx.x & 63;   // 960 blocks: t<15
  __shared__ float T[64][65];
  const float* src = cores + ((size_t)(t*64 + i)*64)*64;  // [d][j]
  for (int idx = threadIdx.x; idx < 4096; idx += 256) {
    int d = idx >> 6, j = idx & 63;
    T[d][j] = src[d*64 + j];
  }
  __syncthreads();
  u16* dst = ws + O_CORT + (size_t)t*CORT_STEP + (size_t)i*64;
  for (int idx = threadIdx.x; idx < 4096; idx += 256) {
    int j = idx >> 6, d = idx & 63;
    dst[(size_t)j*4096 + d] = f2b(T[d][j]);
  }
}

// ---------------- fused ----------------
__global__ __launch_bounds__(256, 2)
void fused(const float* __restrict__ X, const float* __restrict__ init_w,
           const float* __restrict__ b1e, const float* __restrict__ b2e,
           const float* __restrict__ b1n, const float* __restrict__ b2n,
           const float* __restrict__ mub, const float* __restrict__ sgb,
           const float* __restrict__ alb, const u16* __restrict__ ws,
           float* __restrict__ out) {
  __shared__ __align__(16) char Lp[LDS_BYTES];
  const int tid = threadIdx.x;
  const int w = tid >> 6, l = tid & 63, li = l & 15, g = l >> 4;
  const int n0 = blockIdx.x * 64;
  const int sw = (li & 7) << 4;   // s = st*16+li so s&7 == li&7
  float res = 0.f, nrm = 0.f;

  char* TMPc = Lp + LTMPA;
  char* TMPn = Lp + LTMPB;

  // tmp0 init (bf16, swizzled [s][r])
  for (int idx = tid; idx < 4096; idx += 256) {
    int s = idx >> 6, r = idx & 63;
    *(u16*)(TMPc + s*128 + ((2*r) ^ ((s & 7) << 4))) = f2b(init_w[r]);
  }
  { uint4 z = {0,0,0,0};
    for (int idx = tid; idx < 512; idx += 256) *(uint4*)(Lp + LXP + idx*16) = z; }
  if (tid < 64) { float v = init_w[tid]; nrm += 64.f * v * v; }   // norm0
  __syncthreads();

  for (int t = 0; t < 16; ++t) {
    // ---- X load: XT f32 [8][66], XP bf16 [s][d<8] swizzled ----
    for (int idx = tid; idx < 512; idx += 256) {
      int s = idx & 63, d = idx >> 6;
      float x = X[(size_t)(n0 + s)*128 + d*16 + t];
      *(float*)(Lp + LXT + (d*XTS + s)*4) = x;
      *(u16*)(Lp + LXP + s*128 + ((2*d) ^ ((s & 7) << 4))) = f2b(x);
    }
    __syncthreads();

    // ---- phi: h1 (512) -> h2 (64), chunked, 1 barrier/chunk ----
    f32x4 acc2[4];
#pragma unroll
    for (int st = 0; st < 4; ++st) acc2[st] = (f32x4){0.f,0.f,0.f,0.f};
#pragma unroll 1
    for (int oc = 0; oc < 8; ++oc) {
      const u16* a0 = ws + O_W1N + (oc*64 + w*16 + li)*64 + 8*g;
      uint4 af0 = *(const uint4*)a0;
      uint4 af1 = *(const uint4*)(a0 + 32);
      char* H1b = Lp + ((oc & 1) ? LH1B : LH1A);
      float4 bb = *(const float4*)(b1n + oc*64 + w*16 + 4*g);
#pragma unroll
      for (int st = 0; st < 4; ++st) {
        int s = st*16 + li;
        uint4 b0 = *(const uint4*)(TMPc + s*128 + ((16*g) ^ sw));
        uint4 b1 = *(const uint4*)(TMPc + s*128 + ((64 + 16*g) ^ sw));
        f32x4 a1 = (f32x4){0.f,0.f,0.f,0.f};
        a1 = MF(af0, b0, a1); a1 = MF(af1, b1, a1);
        float v0 = fmaxf(a1[0] + bb.x, 0.f), v1 = fmaxf(a1[1] + bb.y, 0.f);
        float v2 = fmaxf(a1[2] + bb.z, 0.f), v3 = fmaxf(a1[3] + bb.w, 0.f);
        *(u32*)(H1b + s*128 + ((32*w + 8*g) ^ sw))     = pk2(v0, v1);
        *(u32*)(H1b + s*128 + ((32*w + 8*g + 4) ^ sw)) = pk2(v2, v3);
      }
      __syncthreads();
      const u16* a2 = ws + O_W2N + (w*16 + li)*512 + oc*64 + 8*g;
      uint4 c0 = *(const uint4*)a2;
      uint4 c1 = *(const uint4*)(a2 + 32);
#pragma unroll
      for (int st = 0; st < 4; ++st) {
        int s = st*16 + li;
        uint4 b0 = *(const uint4*)(H1b + s*128 + ((16*g) ^ sw));
        uint4 b1 = *(const uint4*)(H1b + s*128 + ((64 + 16*g) ^ sw));
        acc2[st] = MF(c0, b0, acc2[st]); acc2[st] = MF(c1, b1, acc2[st]);
      }
    }
    { // h2 epilogue -> H2 bf16
      float4 bb = *(const float4*)(b2n + w*16 + 4*g);
#pragma unroll
      for (int st = 0; st < 4; ++st) {
        int s = st*16 + li;
        float v0 = fmaxf(acc2[st][0] + bb.x, 0.f), v1 = fmaxf(acc2[st][1] + bb.y, 0.f);
        float v2 = fmaxf(acc2[st][2] + bb.z, 0.f), v3 = fmaxf(acc2[st][3] + bb.w, 0.f);
        *(u32*)(Lp + LH2 + s*128 + ((32*w + 8*g) ^ sw))     = pk2(v0, v1);
        *(u32*)(Lp + LH2 + s*128 + ((32*w + 8*g + 4) ^ sw)) = pk2(v2, v3);
      }
    }
    __syncthreads();

    // ---- mu/sig -> comp_lp (registers; CLP via shfl combine) ----
#pragma unroll 1
    for (int c = 0; c < 4; ++c) {
      int ob = c*64 + w*16;
      const u16* as_ = ws + O_SGW + (ob + li)*64 + 8*g;
      const u16* am_ = ws + O_MUW + (ob + li)*64 + 8*g;
      uint4 sf0 = *(const uint4*)as_, sf1 = *(const uint4*)(as_ + 32);
      uint4 mf0 = *(const uint4*)am_, mf1 = *(const uint4*)(am_ + 32);
      float4 bs = *(const float4*)(sgb + ob + 4*g);
      float4 bm = *(const float4*)(mub + ob + 4*g);
      const float bsv[4] = {bs.x, bs.y, bs.z, bs.w};
      const float bmv[4] = {bm.x, bm.y, bm.z, bm.w};
#pragma unroll
      for (int st = 0; st < 4; ++st) {
        int s = st*16 + li;
        uint4 b0 = *(const uint4*)(Lp + LH2 + s*128 + ((16*g) ^ sw));
        uint4 b1 = *(const uint4*)(Lp + LH2 + s*128 + ((64 + 16*g) ^ sw));
        f32x4 aS = (f32x4){0.f,0.f,0.f,0.f}, aM = (f32x4){0.f,0.f,0.f,0.f};
        aS = MF(sf0, b0, aS); aS = MF(sf1, b1, aS);
        aM = MF(mf0, b0, aM); aM = MF(mf1, b1, aM);
        float part = 0.f;
#pragma unroll
        for (int r = 0; r < 4; ++r) {
          int d = (4*g + r) & 7;
          float ls = aS[r] + bsv[r];
          float mu = aM[r] + bmv[r];
          float xv = *(const float*)(Lp + LXT + (d*XTS + s)*4);
          float z = (xv - mu) * __expf(-ls);
          part += -0.5f*z*z - ls - HALF_LOG2PI;
        }
        float comb = part + __shfl_xor(part, 16);
        if (!(g & 1)) {
          int mix = c*8 + 2*w + (g >> 1);
          *(float*)(Lp + LCLP + (mix*64 + s)*4) = comb;
        }
      }
    }
    // ---- alpha logits -> ALPH f32 (wave w handles stile w, both otiles) ----
    {
      int s = w*16 + li;
#pragma unroll
      for (int ot = 0; ot < 2; ++ot) {
        const u16* aa = ws + O_ALW + (ot*16 + li)*64 + 8*g;
        uint4 a0 = *(const uint4*)aa, a1 = *(const uint4*)(aa + 32);
        uint4 b0 = *(const uint4*)(Lp + LH2 + s*128 + ((16*g) ^ sw));
        uint4 b1 = *(const uint4*)(Lp + LH2 + s*128 + ((64 + 16*g) ^ sw));
        f32x4 acc = (f32x4){0.f,0.f,0.f,0.f};
        acc = MF(a0, b0, acc); acc = MF(a1, b1, acc);
        float4 ab4 = *(const float4*)(alb + ot*16 + 4*g);
        const float abv[4] = {ab4.x, ab4.y, ab4.z, ab4.w};
#pragma unroll
        for (int r = 0; r < 4; ++r)
          *(float*)(Lp + LALP + ((ot*16 + 4*g + r)*64 + s)*4) = acc[r] + abv[r];
      }
    }
    __syncthreads();

    // ---- logsumexp(alpha+clp) - logsumexp(alpha) ----
    if (tid < 64) {
      float m1 = -1e30f, m2 = -1e30f;
#pragma unroll 1
      for (int m = 0; m < 32; ++m) {
        float a  = *(const float*)(Lp + LALP + (m*64 + tid)*4);
        float cc = *(const float*)(Lp + LCLP + (m*64 + tid)*4);
        m1 = fmaxf(m1, a + cc); m2 = fmaxf(m2, a);
      }
      float s1 = 0.f, s2 = 0.f;
#pragma unroll 1
      for (int m = 0; m < 32; ++m) {
        float a  = *(const float*)(Lp + LALP + (m*64 + tid)*4);
        float cc = *(const float*)(Lp + LCLP + (m*64 + tid)*4);
        s1 += __expf(a + cc - m1); s2 += __expf(a - m2);
      }
      res += (m1 + __logf(s1)) - (m2 + __logf(s2));
    }
    if (t == 15) break;
    __syncthreads();

    // ---- encoder: he (256, K=32 padded) -> enc (64), chunked ----
    f32x4 acE[4];
#pragma unroll
    for (int st = 0; st < 4; ++st) acE[st] = (f32x4){0.f,0.f,0.f,0.f};
#pragma unroll 1
    for (int ec = 0; ec < 4; ++ec) {
      const u16* ae_ = ws + O_E1W + (ec*64 + w*16 + li)*32 + 8*g;
      uint4 ae = *(const uint4*)ae_;
      char* H1b = Lp + ((ec & 1) ? LH1B : LH1A);
      float4 bb = *(const float4*)(b1e + ec*64 + w*16 + 4*g);
#pragma unroll
      for (int st = 0; st < 4; ++st) {
        int s = st*16 + li;
        uint4 b0 = *(const uint4*)(Lp + LXP + s*128 + ((16*g) ^ sw));
        f32x4 ah = (f32x4){0.f,0.f,0.f,0.f};
        ah = MF(ae, b0, ah);
        float v0 = fmaxf(ah[0] + bb.x, 0.f), v1 = fmaxf(ah[1] + bb.y, 0.f);
        float v2 = fmaxf(ah[2] + bb.z, 0.f), v3 = fmaxf(ah[3] + bb.w, 0.f);
        *(u32*)(H1b + s*128 + ((32*w + 8*g) ^ sw))     = pk2(v0, v1);
        *(u32*)(H1b + s*128 + ((32*w + 8*g + 4) ^ sw)) = pk2(v2, v3);
      }
      __syncthreads();
      const u16* a2 = ws + O_E2W + (w*16 + li)*256 + ec*64 + 8*g;
      uint4 c0 = *(const uint4*)a2, c1 = *(const uint4*)(a2 + 32);
#pragma unroll
      for (int st = 0; st < 4; ++st) {
        int s = st*16 + li;
        uint4 b0 = *(const uint4*)(H1b + s*128 + ((16*g) ^ sw));
        uint4 b1 = *(const uint4*)(H1b + s*128 + ((64 + 16*g) ^ sw));
        acE[st] = MF(c0, b0, acE[st]); acE[st] = MF(c1, b1, acE[st]);
      }
    }
    { // enc epilogue -> ENCF f32 [s][d] swizzled (rows 256B)
      float4 be = *(const float4*)(b2e + w*16 + 4*g);
      const float bev[4] = {be.x, be.y, be.z, be.w};
#pragma unroll
      for (int st = 0; st < 4; ++st) {
        int s = st*16 + li;
#pragma unroll
        for (int r = 0; r < 4; ++r)
          *(float*)(Lp + LENC + s*256 + ((64*w + 16*g + 4*r) ^ sw)) = acE[st][r] + bev[r];
      }
    }
    __syncthreads();

    // ---- update: tmp_new[j][s] = sum_{i,d} coreT[j][i*64+d] * tmp[s][i]*enc[s][d] ----
    f32x4 aU[4];
#pragma unroll
    for (int st = 0; st < 4; ++st) aU[st] = (f32x4){0.f,0.f,0.f,0.f};
    const u16* cort = ws + O_CORT + (size_t)t*CORT_STEP + (w*16 + li)*4096;
    const int bs_ = tid >> 2, bq = tid & 3;
    const int bsw = (bs_ & 7) << 4;
    auto BUILD = [&](int c) {
      int i  = 2*c + (bq >> 1);
      int d0 = (bq & 1) * 32;
      float ts = b2f(*(const u16*)(TMPc + bs_*128 + ((2*i) ^ bsw)));
      char* dst = Lp + ((c & 1) ? 16384 : 0) + bs_*256;
      const char* ef = Lp + LENC + bs_*256;
#pragma unroll
      for (int jj = 0; jj < 4; ++jj) {
        float4 e0 = *(const float4*)(ef + ((4*(d0 + 8*jj))     ^ bsw));
        float4 e1 = *(const float4*)(ef + ((4*(d0 + 8*jj + 4)) ^ bsw));
        uint4 o;
        o.x = pk2(ts*e0.x, ts*e0.y);
        o.y = pk2(ts*e0.z, ts*e0.w);
        o.z = pk2(ts*e1.x, ts*e1.y);
        o.w = pk2(ts*e1.z, ts*e1.w);
        *(uint4*)(dst + ((64*bq + 16*jj) ^ bsw)) = o;
      }
    };
    BUILD(0);
    __syncthreads();
    uint4 a0 = *(const uint4*)(cort + 8*g);
    uint4 a1 = *(const uint4*)(cort + 32 + 8*g);
    uint4 a2 = *(const uint4*)(cort + 64 + 8*g);
    uint4 a3 = *(const uint4*)(cort + 96 + 8*g);
#pragma unroll 1
    for (int c = 0; c < 32; ++c) {
      uint4 na0 = a0, na1 = a1, na2 = a2, na3 = a3;
      if (c < 31) {
        const u16* cn = cort + (c + 1)*128;
        na0 = *(const uint4*)(cn + 8*g);
        na1 = *(const uint4*)(cn + 32 + 8*g);
        na2 = *(const uint4*)(cn + 64 + 8*g);
        na3 = *(const uint4*)(cn + 96 + 8*g);
        BUILD(c + 1);
      }
      const char* Bb = Lp + ((c & 1) ? 16384 : 0);
#pragma unroll
      for (int st = 0; st < 4; ++st) {
        int s = st*16 + li;
        const char* bp = Bb + s*256;
        aU[st] = MF(a0, *(const uint4*)(bp + ((16*g) ^ sw)), aU[st]);
        aU[st] = MF(a1, *(const uint4*)(bp + ((64  + 16*g) ^ sw)), aU[st]);
        aU[st] = MF(a2, *(const uint4*)(bp + ((128 + 16*g) ^ sw)), aU[st]);
        aU[st] = MF(a3, *(const uint4*)(bp + ((192 + 16*g) ^ sw)), aU[st]);
      }
      __syncthreads();
      a0 = na0; a1 = na1; a2 = na2; a3 = na3;
    }
    // epilogue: norm (f32 accs), tmp_new -> TMPn bf16, re-zero XP
#pragma unroll
    for (int st = 0; st < 4; ++st) {
      int s = st*16 + li;
      nrm += aU[st][0]*aU[st][0] + aU[st][1]*aU[st][1]
           + aU[st][2]*aU[st][2] + aU[st][3]*aU[st][3];
      *(u32*)(TMPn + s*128 + ((32*w + 8*g) ^ sw))     = pk2(aU[st][0], aU[st][1]);
      *(u32*)(TMPn + s*128 + ((32*w + 8*g + 4) ^ sw)) = pk2(aU[st][2], aU[st][3]);
    }
    { uint4 z = {0,0,0,0};
      for (int idx = tid; idx < 512; idx += 256) *(uint4*)(Lp + LXP + idx*16) = z; }
    __syncthreads();
    { char* tt = TMPc; TMPc = TMPn; TMPn = tt; }
  } // t loop

  if (tid < 64) out[n0 + tid] = res;
  __syncthreads();
  *(float*)(Lp + LCLP + tid*4) = nrm;
  __syncthreads();
  if (tid < 64) {
    float v = *(const float*)(Lp + LCLP + tid*4)
            + *(const float*)(Lp + LCLP + (tid + 64)*4)
            + *(const float*)(Lp + LCLP + (tid + 128)*4)
            + *(const float*)(Lp + LCLP + (tid + 192)*4);
#pragma unroll
    for (int off = 32; off > 0; off >>= 1) v += __shfl_down(v, off);
    if (tid == 0) atomicAdd(out + NSAMP, v);
  }
}

extern "C" void kernel_launch(void* const* d_in, const int* in_sizes, int n_in,
                              void* d_out, int out_size, void* d_ws, size_t ws_size,
                              hipStream_t stream) {
  const float* X      = (const float*)d_in[0];
  const float* init_w = (const float*)d_in[1];
  const float* cores  = (const float*)d_in[2];
  const float* e1w    = (const float*)d_in[3];
  const float* b1e    = (const float*)d_in[4];
  const float* e2w    = (const float*)d_in[5];
  const float* b2e    = (const float*)d_in[6];
  const float* nw1    = (const float*)d_in[7];
  const float* b1n    = (const float*)d_in[8];
  const float* nw2    = (const float*)d_in[9];
  const float* b2n    = (const float*)d_in[10];
  const float* muw    = (const float*)d_in[11];
  const float* mub    = (const float*)d_in[12];
  const float* sgw    = (const float*)d_in[13];
  const float* sgb    = (const float*)d_in[14];
  const float* alw    = (const float*)d_in[15];
  const float* alb    = (const float*)d_in[16];
  float* out = (float*)d_out;
  u16*   ws  = (u16*)d_ws;

  prep_w<<<64, 256, 0, stream>>>(nw1, nw2, muw, sgw, alw, e1w, e2w, ws, out);
  prep_core<<<960, 256, 0, stream>>>(cores, ws);
  fused<<<NSAMP/64, 256, 0, stream>>>(X, init_w, b1e, b2e, b1n, b2n,
                                      mub, sgb, alb, ws, out);
}

// Round 4
// 928.280 us; speedup vs baseline: 7.2866x; 1.0465x over previous
//
#include <hip/hip_runtime.h>

typedef unsigned short u16;
typedef unsigned int u32;
typedef __attribute__((ext_vector_type(8))) __bf16 bf16x8;
typedef __attribute__((ext_vector_type(4))) float f32x4;

#define NSAMP 32768
#define HALF_LOG2PI 0.91893853320467274f

// ws u16 offsets
#define O_W1N 0
#define O_W2N 32768
#define O_MUW 65536
#define O_SGW 81920
#define O_ALW 98304
#define O_E1W 100352
#define O_E2W 108544
#define O_CORT 124928
#define CORT_STEP 262144

// LDS byte offsets (pool 0..49152 phase-overlaid; total 81920 -> 2 blocks/CU)
#define L_H1A 0
#define L_H1B 8192
#define L_LM1 0          // LSE max bufs overlay H1A
#define L_LM2 1024
#define L_LS1 8192       // LSE sum bufs overlay H1B
#define L_LS2 9216
#define L_PRA 0          // update partials (bf16) overlay H1A
#define L_PRB 8192
#define L_PRC 16384      // overlays H2
#define L_H2  16384
#define L_CLP 24576
#define L_ALP 32768
#define L_XT  40960      // [8][64] f32
#define L_XP  43008      // [64][32] bf16, 16B-granule XOR swizzle
#define L_TMPA 49152
#define L_TMPB 57344
#define L_ENC 65536      // [64 s][64 d] f32, 32B-granule XOR swizzle
#define LDS_BYTES 81920

static __device__ __forceinline__ u16 f2b(float x){ return __builtin_bit_cast(u16,(__bf16)x); }
static __device__ __forceinline__ float b2f(u16 u){ return __builtin_bit_cast(float,((u32)u)<<16); }
static __device__ __forceinline__ float b2flo(u32 v){ return __builtin_bit_cast(float, v<<16); }
static __device__ __forceinline__ float b2fhi(u32 v){ return __builtin_bit_cast(float, v & 0xffff0000u); }
static __device__ __forceinline__ u32 pk2(float lo, float hi){
  return (u32)__builtin_bit_cast(u16,(__bf16)lo) | ((u32)__builtin_bit_cast(u16,(__bf16)hi)<<16);
}
static __device__ __forceinline__ f32x4 MF(uint4 a, uint4 b, f32x4 c){
  union U{uint4 q; bf16x8 v;};
  U A, B; A.q=a; B.q=b;
  return __builtin_amdgcn_mfma_f32_16x16x32_bf16(A.v, B.v, c, 0, 0, 0);
}

// ---------------- prep: weights -> bf16 ----------------
__global__ void prep_w(const float* __restrict__ nw1, const float* __restrict__ nw2,
                       const float* __restrict__ muw, const float* __restrict__ sgw,
                       const float* __restrict__ alw, const float* __restrict__ e1w,
                       const float* __restrict__ e2w, u16* __restrict__ ws,
                       float* __restrict__ out) {
  int idx0 = blockIdx.x * blockDim.x + threadIdx.x;
  int stride = gridDim.x * blockDim.x;
  for (int idx = idx0; idx < 124928; idx += stride) {
    float v;
    if      (idx < 32768)  v = nw1[idx];
    else if (idx < 65536)  v = nw2[idx - 32768];
    else if (idx < 81920)  v = muw[idx - 65536];
    else if (idx < 98304)  v = sgw[idx - 81920];
    else if (idx < 100352) v = alw[idx - 98304];
    else if (idx < 108544) { int j = idx - 100352; int o = j >> 5, k = j & 31;
                             v = (k < 8) ? e1w[o*8 + k] : 0.0f; }
    else                   v = e2w[idx - 108544];
    ws[idx] = f2b(v);
  }
  if (idx0 == 0) out[NSAMP] = 0.0f;
}

// ---------------- prep: cores[t][i][d][j] -> frag-tiled coreT ----------------
// layout: [t][kk(128)][ot(4)][lane(64)][8], k = i*64+d, lane = 16*((k>>3)&3) + (j&15)
__global__ void prep_core(const float* __restrict__ cores, u16* __restrict__ ws) {
  int t = blockIdx.x >> 6, i = blockIdx.x & 63;   // 960 blocks: t<15
  const float* src = cores + ((size_t)(t*64 + i) * 64) * 64;   // [d][j]
  u16* dst = ws + O_CORT + (size_t)t * CORT_STEP;
  for (int idx = threadIdx.x; idx < 4096; idx += 256) {
    int d = idx >> 6, j = idx & 63;
    float v = src[d*64 + j];
    int k = i*64 + d;
    int kk = k >> 5, g = (k >> 3) & 3, b = k & 7;
    int ot = j >> 4, li = j & 15;
    dst[(size_t)(((kk*4 + ot)*64) + g*16 + li)*8 + b] = f2b(v);
  }
}

// ---------------- fused ----------------
__global__ __launch_bounds__(256, 2)
void fused(const float* __restrict__ X, const float* __restrict__ init_w,
           const float* __restrict__ b1e, const float* __restrict__ b2e,
           const float* __restrict__ b1n, const float* __restrict__ b2n,
           const float* __restrict__ mub, const float* __restrict__ sgb,
           const float* __restrict__ alb, const u16* __restrict__ ws,
           float* __restrict__ out) {
  __shared__ __align__(16) char Lp[LDS_BYTES];
  const int tid = threadIdx.x;
  const int w = tid >> 6, l = tid & 63, li = l & 15, g = l >> 4;
  const int e3 = li & 7;
  const int sw = e3 << 4;
  const int n0 = blockIdx.x * 64;
  float res = 0.f, nrm = 0.f;

  char* TMPc = Lp + L_TMPA;
  char* TMPn = Lp + L_TMPB;

  // init: tmp0 bf16 swizzled [s][r]; XP zero; norm0
  for (int idx = tid; idx < 4096; idx += 256) {
    int s = idx >> 6, r = idx & 63;
    *(u16*)(TMPc + s*128 + ((2*r) ^ ((s & 7) << 4))) = f2b(init_w[r]);
  }
  { uint4 z = {0,0,0,0};
    *(uint4*)(Lp + L_XP + tid*16) = z; }   // 256*16 = 4096 B
  if (tid < 64) { float v = init_w[tid]; nrm += 64.f * v * v; }
  __syncthreads();

  for (int t = 0; t < 16; ++t) {
    // ---- X load: XT f32 [8][64]; XP bf16 [s][32k] granule-swizzled ----
    for (int idx = tid; idx < 512; idx += 256) {
      int d = idx >> 6, s = idx & 63;
      float x = X[(size_t)(n0 + s)*128 + d*16 + t];
      *(float*)(Lp + L_XT + (d*64 + s)*4) = x;
      *(u16*)(Lp + L_XP + s*64 + ((2*d) ^ ((s & 3) << 4))) = f2b(x);
    }
    // (no barrier: XT/XP consumed many barriers later)

    // ---- phi h1(512)->h2(64): 9-phase pipeline, 1 barrier/phase ----
    f32x4 acc2[4];
#pragma unroll
    for (int st = 0; st < 4; ++st) acc2[st] = (f32x4){0.f,0.f,0.f,0.f};
#pragma unroll 1
    for (int p = 0; p <= 8; ++p) {
      if (p < 8) {
        const u16* a0p = ws + O_W1N + (p*64 + w*16 + li)*64 + 8*g;
        uint4 af0 = *(const uint4*)a0p;
        uint4 af1 = *(const uint4*)(a0p + 32);
        float4 bb = *(const float4*)(b1n + p*64 + w*16 + 4*g);
        char* H1b = Lp + ((p & 1) ? L_H1B : L_H1A);
#pragma unroll
        for (int st = 0; st < 4; ++st) {
          int s = st*16 + li;
          uint4 b0 = *(const uint4*)(TMPc + s*128 + ((16*g) ^ sw));
          uint4 b1 = *(const uint4*)(TMPc + s*128 + ((64 + 16*g) ^ sw));
          f32x4 a1 = (f32x4){0.f,0.f,0.f,0.f};
          a1 = MF(af0, b0, a1); a1 = MF(af1, b1, a1);
          float v0 = fmaxf(a1[0] + bb.x, 0.f), v1 = fmaxf(a1[1] + bb.y, 0.f);
          float v2 = fmaxf(a1[2] + bb.z, 0.f), v3 = fmaxf(a1[3] + bb.w, 0.f);
          *(u32*)(H1b + s*128 + ((32*w + 8*g) ^ sw))     = pk2(v0, v1);
          *(u32*)(H1b + s*128 + ((32*w + 8*g + 4) ^ sw)) = pk2(v2, v3);
        }
      }
      if (p > 0) {
        int q = p - 1;
        const u16* a2p = ws + O_W2N + (w*16 + li)*512 + q*64 + 8*g;
        uint4 c0 = *(const uint4*)a2p;
        uint4 c1 = *(const uint4*)(a2p + 32);
        const char* H1r = Lp + ((q & 1) ? L_H1B : L_H1A);
#pragma unroll
        for (int st = 0; st < 4; ++st) {
          int s = st*16 + li;
          uint4 b0 = *(const uint4*)(H1r + s*128 + ((16*g) ^ sw));
          uint4 b1 = *(const uint4*)(H1r + s*128 + ((64 + 16*g) ^ sw));
          acc2[st] = MF(c0, b0, acc2[st]); acc2[st] = MF(c1, b1, acc2[st]);
        }
      }
      __syncthreads();
    }
    { // h2 epilogue -> H2 bf16 swizzled
      float4 bb = *(const float4*)(b2n + w*16 + 4*g);
#pragma unroll
      for (int st = 0; st < 4; ++st) {
        int s = st*16 + li;
        float v0 = fmaxf(acc2[st][0] + bb.x, 0.f), v1 = fmaxf(acc2[st][1] + bb.y, 0.f);
        float v2 = fmaxf(acc2[st][2] + bb.z, 0.f), v3 = fmaxf(acc2[st][3] + bb.w, 0.f);
        *(u32*)(Lp + L_H2 + s*128 + ((32*w + 8*g) ^ sw))     = pk2(v0, v1);
        *(u32*)(Lp + L_H2 + s*128 + ((32*w + 8*g + 4) ^ sw)) = pk2(v2, v3);
      }
    }
    __syncthreads();

    // ---- mu/sig -> comp_lp (registers, shfl combine) ----
#pragma unroll 1
    for (int c = 0; c < 4; ++c) {
      int ob = c*64 + w*16;
      const u16* as_ = ws + O_SGW + (ob + li)*64 + 8*g;
      const u16* am_ = ws + O_MUW + (ob + li)*64 + 8*g;
      uint4 sf0 = *(const uint4*)as_, sf1 = *(const uint4*)(as_ + 32);
      uint4 mf0 = *(const uint4*)am_, mf1 = *(const uint4*)(am_ + 32);
      float4 bs = *(const float4*)(sgb + ob + 4*g);
      float4 bm = *(const float4*)(mub + ob + 4*g);
      const float bsv[4] = {bs.x,bs.y,bs.z,bs.w};
      const float bmv[4] = {bm.x,bm.y,bm.z,bm.w};
#pragma unroll
      for (int st = 0; st < 4; ++st) {
        int s = st*16 + li;
        uint4 b0 = *(const uint4*)(Lp + L_H2 + s*128 + ((16*g) ^ sw));
        uint4 b1 = *(const uint4*)(Lp + L_H2 + s*128 + ((64 + 16*g) ^ sw));
        f32x4 aS = (f32x4){0.f,0.f,0.f,0.f}, aM = (f32x4){0.f,0.f,0.f,0.f};
        aS = MF(sf0, b0, aS); aS = MF(sf1, b1, aS);
        aM = MF(mf0, b0, aM); aM = MF(mf1, b1, aM);
        float part = 0.f;
#pragma unroll
        for (int r = 0; r < 4; ++r) {
          int d = (4*g + r) & 7;
          float ls = aS[r] + bsv[r];
          float mu = aM[r] + bmv[r];
          float xv = *(const float*)(Lp + L_XT + (d*64 + s)*4);
          float z = (xv - mu) * __expf(-ls);
          part += -0.5f*z*z - ls - HALF_LOG2PI;
        }
        float comb = part + __shfl_xor(part, 16);
        if (!(g & 1)) {
          int mix = c*8 + 2*w + (g >> 1);
          *(float*)(Lp + L_CLP + (mix*64 + s)*4) = comb;
        }
      }
    }
    // ---- alpha logits -> ALP f32 ----
    {
      int s = w*16 + li;
#pragma unroll
      for (int ot = 0; ot < 2; ++ot) {
        const u16* aa = ws + O_ALW + (ot*16 + li)*64 + 8*g;
        uint4 a0 = *(const uint4*)aa, a1 = *(const uint4*)(aa + 32);
        uint4 b0 = *(const uint4*)(Lp + L_H2 + s*128 + ((16*g) ^ sw));
        uint4 b1 = *(const uint4*)(Lp + L_H2 + s*128 + ((64 + 16*g) ^ sw));
        f32x4 acc = (f32x4){0.f,0.f,0.f,0.f};
        acc = MF(a0, b0, acc); acc = MF(a1, b1, acc);
        float4 ab4 = *(const float4*)(alb + ot*16 + 4*g);
        const float abv[4] = {ab4.x, ab4.y, ab4.z, ab4.w};
#pragma unroll
        for (int r = 0; r < 4; ++r)
          *(float*)(Lp + L_ALP + ((ot*16 + 4*g + r)*64 + s)*4) = acc[r] + abv[r];
      }
    }
    __syncthreads();

    // ---- parallel LSE: 256 threads, 8 m each ----
    float g1, g2;
    {
      int s = l;
      float m1 = -1e30f, m2 = -1e30f;
#pragma unroll
      for (int mm = 0; mm < 8; ++mm) {
        int m = w*8 + mm;
        float a = *(const float*)(Lp + L_ALP + (m*64 + s)*4);
        float c = *(const float*)(Lp + L_CLP + (m*64 + s)*4);
        m1 = fmaxf(m1, a + c); m2 = fmaxf(m2, a);
      }
      *(float*)(Lp + L_LM1 + (w*64 + s)*4) = m1;
      *(float*)(Lp + L_LM2 + (w*64 + s)*4) = m2;
      __syncthreads();
      g1 = fmaxf(fmaxf(*(const float*)(Lp + L_LM1 + s*4),
                       *(const float*)(Lp + L_LM1 + (64 + s)*4)),
                 fmaxf(*(const float*)(Lp + L_LM1 + (128 + s)*4),
                       *(const float*)(Lp + L_LM1 + (192 + s)*4)));
      g2 = fmaxf(fmaxf(*(const float*)(Lp + L_LM2 + s*4),
                       *(const float*)(Lp + L_LM2 + (64 + s)*4)),
                 fmaxf(*(const float*)(Lp + L_LM2 + (128 + s)*4),
                       *(const float*)(Lp + L_LM2 + (192 + s)*4)));
      float s1 = 0.f, s2 = 0.f;
#pragma unroll
      for (int mm = 0; mm < 8; ++mm) {
        int m = w*8 + mm;
        float a = *(const float*)(Lp + L_ALP + (m*64 + s)*4);
        float c = *(const float*)(Lp + L_CLP + (m*64 + s)*4);
        s1 += __expf(a + c - g1); s2 += __expf(a - g2);
      }
      *(float*)(Lp + L_LS1 + (w*64 + s)*4) = s1;
      *(float*)(Lp + L_LS2 + (w*64 + s)*4) = s2;
      __syncthreads();
    }
    if (tid < 64) {
      float s1 = *(const float*)(Lp + L_LS1 + tid*4)
               + *(const float*)(Lp + L_LS1 + (64 + tid)*4)
               + *(const float*)(Lp + L_LS1 + (128 + tid)*4)
               + *(const float*)(Lp + L_LS1 + (192 + tid)*4);
      float s2 = *(const float*)(Lp + L_LS2 + tid*4)
               + *(const float*)(Lp + L_LS2 + (64 + tid)*4)
               + *(const float*)(Lp + L_LS2 + (128 + tid)*4)
               + *(const float*)(Lp + L_LS2 + (192 + tid)*4);
      res += (g1 + __logf(s1)) - (g2 + __logf(s2));
    }
    if (t == 15) break;

    // ---- encoder: 5-phase pipeline ----
    f32x4 acE[4];
#pragma unroll
    for (int st = 0; st < 4; ++st) acE[st] = (f32x4){0.f,0.f,0.f,0.f};
#pragma unroll 1
    for (int p = 0; p <= 4; ++p) {
      if (p < 4) {
        const u16* aep = ws + O_E1W + (p*64 + w*16 + li)*32 + 8*g;
        uint4 ae = *(const uint4*)aep;
        float4 bb = *(const float4*)(b1e + p*64 + w*16 + 4*g);
        char* H1b = Lp + ((p & 1) ? L_H1B : L_H1A);
#pragma unroll
        for (int st = 0; st < 4; ++st) {
          int s = st*16 + li;
          uint4 b0 = *(const uint4*)(Lp + L_XP + s*64 + ((16*g) ^ ((s & 3) << 4)));
          f32x4 ah = (f32x4){0.f,0.f,0.f,0.f};
          ah = MF(ae, b0, ah);
          float v0 = fmaxf(ah[0] + bb.x, 0.f), v1 = fmaxf(ah[1] + bb.y, 0.f);
          float v2 = fmaxf(ah[2] + bb.z, 0.f), v3 = fmaxf(ah[3] + bb.w, 0.f);
          *(u32*)(H1b + s*128 + ((32*w + 8*g) ^ sw))     = pk2(v0, v1);
          *(u32*)(H1b + s*128 + ((32*w + 8*g + 4) ^ sw)) = pk2(v2, v3);
        }
      }
      if (p > 0) {
        int q = p - 1;
        const u16* c0p = ws + O_E2W + (w*16 + li)*256 + q*64 + 8*g;
        uint4 c0 = *(const uint4*)c0p, c1 = *(const uint4*)(c0p + 32);
        const char* H1r = Lp + ((q & 1) ? L_H1B : L_H1A);
#pragma unroll
        for (int st = 0; st < 4; ++st) {
          int s = st*16 + li;
          uint4 b0 = *(const uint4*)(H1r + s*128 + ((16*g) ^ sw));
          uint4 b1 = *(const uint4*)(H1r + s*128 + ((64 + 16*g) ^ sw));
          acE[st] = MF(c0, b0, acE[st]); acE[st] = MF(c1, b1, acE[st]);
        }
      }
      if (p == 4) { // ENC epilogue: f32, 32B-granule XOR swizzle
        float4 be = *(const float4*)(b2e + w*16 + 4*g);
        const float bev[4] = {be.x, be.y, be.z, be.w};
#pragma unroll
        for (int st = 0; st < 4; ++st) {
          int s = st*16 + li;
#pragma unroll
          for (int r = 0; r < 4; ++r) {
            int d = w*16 + 4*g + r;
            *(float*)(Lp + L_ENC + s*256 + ((((d >> 3) ^ e3)) << 5) + ((d & 7) << 2))
                = acE[st][r] + bev[r];
          }
        }
      }
      __syncthreads();
    }

    // ---- update: K-split across waves, B built in registers ----
    f32x4 aU[4][4];
#pragma unroll
    for (int ot = 0; ot < 4; ++ot)
#pragma unroll
      for (int st = 0; st < 4; ++st) aU[ot][st] = (f32x4){0.f,0.f,0.f,0.f};

    const u16* Abase = ws + O_CORT + (size_t)t*CORT_STEP + (size_t)(w*32)*2048 + (size_t)l*8;
    uint4 A0 = *(const uint4*)(Abase);
    uint4 A1 = *(const uint4*)(Abase + 512);
    uint4 A2 = *(const uint4*)(Abase + 1024);
    uint4 A3 = *(const uint4*)(Abase + 1536);
#pragma unroll 1
    for (int kk = 0; kk < 32; ++kk) {
      uint4 nA0, nA1, nA2, nA3;
      if (kk < 31) {
        const u16* ap = Abase + (size_t)(kk + 1)*2048;
        nA0 = *(const uint4*)(ap);
        nA1 = *(const uint4*)(ap + 512);
        nA2 = *(const uint4*)(ap + 1024);
        nA3 = *(const uint4*)(ap + 1536);
      }
      int kwa = w*32 + kk;
      int h = kwa & 1;
      int tof = (kwa & ~1) ^ sw;                      // (2*i_row) ^ sw
      int eof = ((((h << 2) | g) ^ e3) << 5);         // ENC granule byte offset
      uint4 B[4];
#pragma unroll
      for (int st = 0; st < 4; ++st) {
        int s = st*16 + li;
        float ts = b2f(*(const u16*)(TMPc + s*128 + tof));
        const char* ep = Lp + L_ENC + s*256 + eof;
        float4 e0 = *(const float4*)(ep);
        float4 e1 = *(const float4*)(ep + 16);
        uint4 bb;
        bb.x = pk2(ts*e0.x, ts*e0.y); bb.y = pk2(ts*e0.z, ts*e0.w);
        bb.z = pk2(ts*e1.x, ts*e1.y); bb.w = pk2(ts*e1.z, ts*e1.w);
        B[st] = bb;
      }
      __builtin_amdgcn_s_setprio(1);
#pragma unroll
      for (int ot = 0; ot < 4; ++ot) {
        uint4 Af = (ot == 0) ? A0 : (ot == 1) ? A1 : (ot == 2) ? A2 : A3;
#pragma unroll
        for (int st = 0; st < 4; ++st)
          aU[ot][st] = MF(Af, B[st], aU[ot][st]);
      }
      __builtin_amdgcn_s_setprio(0);
      A0 = nA0; A1 = nA1; A2 = nA2; A3 = nA3;
    }

    // ---- cross-wave K-reduction (bf16 partials) ----
    if (w >= 2) {
      char* pr = Lp + ((w == 2) ? L_PRA : L_PRB);
#pragma unroll
      for (int ot = 0; ot < 4; ++ot)
#pragma unroll
        for (int st = 0; st < 4; ++st) {
          uint2 pv;
          pv.x = pk2(aU[ot][st][0], aU[ot][st][1]);
          pv.y = pk2(aU[ot][st][2], aU[ot][st][3]);
          *(uint2*)(pr + (st*16 + li)*128 + 8*(((ot << 2) | g) ^ e3)) = pv;
        }
    }
    __syncthreads();
    if (w < 2) {
      const char* pr = Lp + ((w == 0) ? L_PRA : L_PRB);
#pragma unroll
      for (int ot = 0; ot < 4; ++ot)
#pragma unroll
        for (int st = 0; st < 4; ++st) {
          uint2 pv = *(const uint2*)(pr + (st*16 + li)*128 + 8*(((ot << 2) | g) ^ e3));
          aU[ot][st][0] += b2flo(pv.x); aU[ot][st][1] += b2fhi(pv.x);
          aU[ot][st][2] += b2flo(pv.y); aU[ot][st][3] += b2fhi(pv.y);
        }
      // cross-write the half this wave does NOT own
      int stb = (w == 0) ? 2 : 0;
#pragma unroll
      for (int sto = 0; sto < 2; ++sto) {
        int st = stb + sto;
#pragma unroll
        for (int ot = 0; ot < 4; ++ot) {
          uint2 pv;
          pv.x = pk2(aU[ot][st][0], aU[ot][st][1]);
          pv.y = pk2(aU[ot][st][2], aU[ot][st][3]);
          *(uint2*)(Lp + L_PRC + (st*16 + li)*128 + 8*(((ot << 2) | g) ^ e3)) = pv;
        }
      }
    }
    __syncthreads();
    if (w < 2) {
      int stb = (w == 0) ? 0 : 2;   // owned half
#pragma unroll
      for (int sto = 0; sto < 2; ++sto) {
        int st = stb + sto;
        int s = st*16 + li;
#pragma unroll
        for (int ot = 0; ot < 4; ++ot) {
          uint2 pv = *(const uint2*)(Lp + L_PRC + (st*16 + li)*128 + 8*(((ot << 2) | g) ^ e3));
          float v0 = aU[ot][st][0] + b2flo(pv.x);
          float v1 = aU[ot][st][1] + b2fhi(pv.x);
          float v2 = aU[ot][st][2] + b2flo(pv.y);
          float v3 = aU[ot][st][3] + b2fhi(pv.y);
          nrm += v0*v0 + v1*v1 + v2*v2 + v3*v3;
          *(u32*)(TMPn + s*128 + ((32*ot + 8*g) ^ sw))     = pk2(v0, v1);
          *(u32*)(TMPn + s*128 + ((32*ot + 8*g + 4) ^ sw)) = pk2(v2, v3);
        }
      }
    }
    __syncthreads();
    { char* tt = TMPc; TMPc = TMPn; TMPn = tt; }
  } // t loop

  if (tid < 64) out[n0 + tid] = res;

  __syncthreads();
  *(float*)(Lp + tid*4) = nrm;
  __syncthreads();
  if (tid < 64) {
    float v = *(const float*)(Lp + tid*4)
            + *(const float*)(Lp + (tid + 64)*4)
            + *(const float*)(Lp + (tid + 128)*4)
            + *(const float*)(Lp + (tid + 192)*4);
#pragma unroll
    for (int off = 32; off > 0; off >>= 1) v += __shfl_down(v, off);
    if (tid == 0) atomicAdd(out + NSAMP, v);
  }
}

extern "C" void kernel_launch(void* const* d_in, const int* in_sizes, int n_in,
                              void* d_out, int out_size, void* d_ws, size_t ws_size,
                              hipStream_t stream) {
  const float* X      = (const float*)d_in[0];
  const float* init_w = (const float*)d_in[1];
  const float* cores  = (const float*)d_in[2];
  const float* e1w    = (const float*)d_in[3];
  const float* b1e    = (const float*)d_in[4];
  const float* e2w    = (const float*)d_in[5];
  const float* b2e    = (const float*)d_in[6];
  const float* nw1    = (const float*)d_in[7];
  const float* b1n    = (const float*)d_in[8];
  const float* nw2    = (const float*)d_in[9];
  const float* b2n    = (const float*)d_in[10];
  const float* muw    = (const float*)d_in[11];
  const float* mub    = (const float*)d_in[12];
  const float* sgw    = (const float*)d_in[13];
  const float* sgb    = (const float*)d_in[14];
  const float* alw    = (const float*)d_in[15];
  const float* alb    = (const float*)d_in[16];
  float* out = (float*)d_out;
  u16*   ws  = (u16*)d_ws;

  prep_w<<<64, 256, 0, stream>>>(nw1, nw2, muw, sgw, alw, e1w, e2w, ws, out);
  prep_core<<<960, 256, 0, stream>>>(cores, ws);
  fused<<<NSAMP/64, 256, 0, stream>>>(X, init_w, b1e, b2e, b1n, b2n,
                                      mub, sgb, alb, ws, out);
}

// Round 5
// 906.001 us; speedup vs baseline: 7.4658x; 1.0246x over previous
//
#include <hip/hip_runtime.h>

typedef unsigned short u16;
typedef unsigned int u32;
typedef __attribute__((ext_vector_type(8))) __bf16 bf16x8;
typedef __attribute__((ext_vector_type(4))) float f32x4;

#define NSAMP 32768
#define HALF_LOG2PI 0.91893853320467274f

// ws u16 offsets
#define O_W1N 0
#define O_W2N 32768
#define O_MUW 65536
#define O_SGW 81920
#define O_ALW 98304
#define O_E1W 100352
#define O_E2W 108544
#define O_CORT 124928
#define CORT_STEP 262144   // 64 d * 64 j * 64 i u16 per step

// LDS byte offsets (52 KB -> 3 blocks/CU)
#define L_TMP 0        // 8192: tmp [s][128B] bf16, XOR-swizzled
#define L_ENC 8192     // 16384: enc [s][256B] f32, 32B-granule XOR swizzle
#define L_H1A 24576    // phi/enc staging A (8KB)
#define L_H1B 32768    // staging B (8KB)
#define L_CLP 24576    // overlay: comp_lp [32][64] f32
#define L_ALP 32768    // overlay: alpha   [32][64] f32
#define L_H2  40960    // 8192: h2 bf16 [s][128B]
#define L_LM1 40960    // LSE overlays (H2 dead by LSE)
#define L_LM2 41984
#define L_LS1 43008
#define L_LS2 44032
#define L_XP  49152    // 4096: x bf16 [s][32k], 16B-granule XOR swizzle
#define LDS_BYTES 53248

static __device__ __forceinline__ u16 f2b(float x){ return __builtin_bit_cast(u16,(__bf16)x); }
static __device__ __forceinline__ float b2f(u16 u){ return __builtin_bit_cast(float,((u32)u)<<16); }
static __device__ __forceinline__ float b2flo(u32 v){ return __builtin_bit_cast(float, v<<16); }
static __device__ __forceinline__ float b2fhi(u32 v){ return __builtin_bit_cast(float, v & 0xffff0000u); }
static __device__ __forceinline__ u32 pk2(float lo, float hi){
  return (u32)__builtin_bit_cast(u16,(__bf16)lo) | ((u32)__builtin_bit_cast(u16,(__bf16)hi)<<16);
}
static __device__ __forceinline__ f32x4 MF(uint4 a, uint4 b, f32x4 c){
  union U{uint4 q; bf16x8 v;};
  U A, B; A.q=a; B.q=b;
  return __builtin_amdgcn_mfma_f32_16x16x32_bf16(A.v, B.v, c, 0, 0, 0);
}

// ---------------- prep: weights -> bf16 (k-contiguous rows) ----------------
__global__ void prep_w(const float* __restrict__ nw1, const float* __restrict__ nw2,
                       const float* __restrict__ muw, const float* __restrict__ sgw,
                       const float* __restrict__ alw, const float* __restrict__ e1w,
                       const float* __restrict__ e2w, u16* __restrict__ ws,
                       float* __restrict__ out) {
  int idx0 = blockIdx.x * blockDim.x + threadIdx.x;
  int stride = gridDim.x * blockDim.x;
  for (int idx = idx0; idx < 124928; idx += stride) {
    float v;
    if      (idx < 32768)  v = nw1[idx];
    else if (idx < 65536)  v = nw2[idx - 32768];
    else if (idx < 81920)  v = muw[idx - 65536];
    else if (idx < 98304)  v = sgw[idx - 81920];
    else if (idx < 100352) v = alw[idx - 98304];
    else if (idx < 108544) { int j = idx - 100352; int o = j >> 5, k = j & 31;
                             v = (k < 8) ? e1w[o*8 + k] : 0.0f; }
    else                   v = e2w[idx - 108544];
    ws[idx] = f2b(v);
  }
  if (idx0 == 0) out[NSAMP] = 0.0f;
}

// ---------------- prep: cores[t][i][d][j] -> coreJI[t][d][j][i] bf16 ----------------
__global__ void prep_core(const float* __restrict__ cores, u16* __restrict__ ws) {
  int t = blockIdx.x >> 6, d = blockIdx.x & 63;   // 960 blocks (t<15)
  __shared__ float T[64][65];
  for (int idx = threadIdx.x; idx < 4096; idx += 256) {
    int i = idx >> 6, j = idx & 63;
    T[i][j] = cores[((size_t)(t*64 + i)*64 + d)*64 + j];
  }
  __syncthreads();
  u16* dst = ws + O_CORT + (size_t)t*CORT_STEP + (size_t)d*4096;
  for (int idx = threadIdx.x; idx < 4096; idx += 256) {
    int j = idx >> 6, i = idx & 63;
    dst[j*64 + i] = f2b(T[i][j]);
  }
}

// ---------------- fused ----------------
__global__ __launch_bounds__(256, 3)
void fused(const float* __restrict__ X, const float* __restrict__ init_w,
           const float* __restrict__ b1e, const float* __restrict__ b2e,
           const float* __restrict__ b1n, const float* __restrict__ b2n,
           const float* __restrict__ mub, const float* __restrict__ sgb,
           const float* __restrict__ alb, const u16* __restrict__ ws,
           float* __restrict__ out) {
  __shared__ __align__(16) char Lp[LDS_BYTES];
  const int tid = threadIdx.x;
  const int w = tid >> 6, l = tid & 63, li = l & 15, g = l >> 4;
  const int e3 = li & 7;
  const int sw = e3 << 4;
  const int n0 = blockIdx.x * 64;
  float res = 0.f, nrm = 0.f;

  // init: tmp0 bf16 swizzled [s][r]; XP zero; norm0
  for (int idx = tid; idx < 4096; idx += 256) {
    int s = idx >> 6, r = idx & 63;
    *(u16*)(Lp + L_TMP + s*128 + ((2*r) ^ ((s & 7) << 4))) = f2b(init_w[r]);
  }
  { uint4 z = {0,0,0,0};
    *(uint4*)(Lp + L_XP + tid*16) = z; }
  if (tid < 64) { float v = init_w[tid]; nrm += 64.f * v * v; }
  __syncthreads();

  for (int t = 0; t < 16; ++t) {
    // ---- X load -> XP bf16 [s][32k] 16B-granule swizzled ----
    for (int idx = tid; idx < 512; idx += 256) {
      int d = idx >> 6, s = idx & 63;
      float x = X[(size_t)(n0 + s)*128 + d*16 + t];
      *(u16*)(Lp + L_XP + s*64 + ((2*d) ^ ((s & 3) << 4))) = f2b(x);
    }

    // ---- tmp fragments: load ONCE (used by phi h1 AND the update) ----
    uint4 Bq0[4], Bq1[4];
#pragma unroll
    for (int st = 0; st < 4; ++st) {
      int s = st*16 + li;
      Bq0[st] = *(const uint4*)(Lp + L_TMP + s*128 + ((16*g) ^ sw));
      Bq1[st] = *(const uint4*)(Lp + L_TMP + s*128 + ((64 + 16*g) ^ sw));
    }

    // ---- phi h1(512)->h2(64): 9-phase pipeline ----
    f32x4 acc2[4];
#pragma unroll
    for (int st = 0; st < 4; ++st) acc2[st] = (f32x4){0.f,0.f,0.f,0.f};
#pragma unroll 1
    for (int p = 0; p <= 8; ++p) {
      if (p < 8) {
        const u16* a0p = ws + O_W1N + (p*64 + w*16 + li)*64 + 8*g;
        uint4 af0 = *(const uint4*)a0p;
        uint4 af1 = *(const uint4*)(a0p + 32);
        float4 bb = *(const float4*)(b1n + p*64 + w*16 + 4*g);
        char* H1b = Lp + ((p & 1) ? L_H1B : L_H1A);
#pragma unroll
        for (int st = 0; st < 4; ++st) {
          int s = st*16 + li;
          f32x4 a1 = (f32x4){0.f,0.f,0.f,0.f};
          a1 = MF(af0, Bq0[st], a1); a1 = MF(af1, Bq1[st], a1);
          float v0 = fmaxf(a1[0] + bb.x, 0.f), v1 = fmaxf(a1[1] + bb.y, 0.f);
          float v2 = fmaxf(a1[2] + bb.z, 0.f), v3 = fmaxf(a1[3] + bb.w, 0.f);
          *(u32*)(H1b + s*128 + ((32*w + 8*g) ^ sw))     = pk2(v0, v1);
          *(u32*)(H1b + s*128 + ((32*w + 8*g + 4) ^ sw)) = pk2(v2, v3);
        }
      }
      if (p > 0) {
        int q = p - 1;
        const u16* a2p = ws + O_W2N + (w*16 + li)*512 + q*64 + 8*g;
        uint4 c0 = *(const uint4*)a2p;
        uint4 c1 = *(const uint4*)(a2p + 32);
        const char* H1r = Lp + ((q & 1) ? L_H1B : L_H1A);
#pragma unroll
        for (int st = 0; st < 4; ++st) {
          int s = st*16 + li;
          uint4 b0 = *(const uint4*)(H1r + s*128 + ((16*g) ^ sw));
          uint4 b1 = *(const uint4*)(H1r + s*128 + ((64 + 16*g) ^ sw));
          acc2[st] = MF(c0, b0, acc2[st]); acc2[st] = MF(c1, b1, acc2[st]);
        }
      }
      __syncthreads();
    }
    { // h2 epilogue -> H2 bf16 swizzled
      float4 bb = *(const float4*)(b2n + w*16 + 4*g);
#pragma unroll
      for (int st = 0; st < 4; ++st) {
        int s = st*16 + li;
        float v0 = fmaxf(acc2[st][0] + bb.x, 0.f), v1 = fmaxf(acc2[st][1] + bb.y, 0.f);
        float v2 = fmaxf(acc2[st][2] + bb.z, 0.f), v3 = fmaxf(acc2[st][3] + bb.w, 0.f);
        *(u32*)(Lp + L_H2 + s*128 + ((32*w + 8*g) ^ sw))     = pk2(v0, v1);
        *(u32*)(Lp + L_H2 + s*128 + ((32*w + 8*g + 4) ^ sw)) = pk2(v2, v3);
      }
    }
    __syncthreads();

    // ---- hoist x values for musig: 4 b64 reads ----
    float xv[4][4];
#pragma unroll
    for (int st = 0; st < 4; ++st) {
      int s = st*16 + li;
      uint2 xq = *(const uint2*)(Lp + L_XP + s*64 + ((8*(g & 1)) ^ ((li & 3) << 4)));
      xv[st][0] = b2flo(xq.x); xv[st][1] = b2fhi(xq.x);
      xv[st][2] = b2flo(xq.y); xv[st][3] = b2fhi(xq.y);
    }

    // ---- mu/sig -> comp_lp (registers, shfl combine) ----
#pragma unroll 1
    for (int c = 0; c < 4; ++c) {
      int ob = c*64 + w*16;
      const u16* as_ = ws + O_SGW + (ob + li)*64 + 8*g;
      const u16* am_ = ws + O_MUW + (ob + li)*64 + 8*g;
      uint4 sf0 = *(const uint4*)as_, sf1 = *(const uint4*)(as_ + 32);
      uint4 mf0 = *(const uint4*)am_, mf1 = *(const uint4*)(am_ + 32);
      float4 bs = *(const float4*)(sgb + ob + 4*g);
      float4 bm = *(const float4*)(mub + ob + 4*g);
      const float bsv[4] = {bs.x,bs.y,bs.z,bs.w};
      const float bmv[4] = {bm.x,bm.y,bm.z,bm.w};
#pragma unroll
      for (int st = 0; st < 4; ++st) {
        int s = st*16 + li;
        uint4 b0 = *(const uint4*)(Lp + L_H2 + s*128 + ((16*g) ^ sw));
        uint4 b1 = *(const uint4*)(Lp + L_H2 + s*128 + ((64 + 16*g) ^ sw));
        f32x4 aS = (f32x4){0.f,0.f,0.f,0.f}, aM = (f32x4){0.f,0.f,0.f,0.f};
        aS = MF(sf0, b0, aS); aS = MF(sf1, b1, aS);
        aM = MF(mf0, b0, aM); aM = MF(mf1, b1, aM);
        float part = 0.f;
#pragma unroll
        for (int r = 0; r < 4; ++r) {
          float ls = aS[r] + bsv[r];
          float mu = aM[r] + bmv[r];
          float z = (xv[st][r] - mu) * __expf(-ls);
          part += -0.5f*z*z - ls - HALF_LOG2PI;
        }
        float comb = part + __shfl_xor(part, 16);
        if (!(g & 1)) {
          int mix = c*8 + 2*w + (g >> 1);
          *(float*)(Lp + L_CLP + (mix*64 + s)*4) = comb;
        }
      }
    }
    // ---- alpha logits -> ALP f32 ----
    {
      int s = w*16 + li;
      uint4 b0 = *(const uint4*)(Lp + L_H2 + s*128 + ((16*g) ^ sw));
      uint4 b1 = *(const uint4*)(Lp + L_H2 + s*128 + ((64 + 16*g) ^ sw));
#pragma unroll
      for (int ot = 0; ot < 2; ++ot) {
        const u16* aa = ws + O_ALW + (ot*16 + li)*64 + 8*g;
        uint4 a0 = *(const uint4*)aa, a1 = *(const uint4*)(aa + 32);
        f32x4 acc = (f32x4){0.f,0.f,0.f,0.f};
        acc = MF(a0, b0, acc); acc = MF(a1, b1, acc);
        float4 ab4 = *(const float4*)(alb + ot*16 + 4*g);
        const float abv[4] = {ab4.x, ab4.y, ab4.z, ab4.w};
#pragma unroll
        for (int r = 0; r < 4; ++r)
          *(float*)(Lp + L_ALP + ((ot*16 + 4*g + r)*64 + s)*4) = acc[r] + abv[r];
      }
    }
    __syncthreads();

    // ---- parallel LSE ----
    float g1, g2;
    {
      int s = l;
      float m1 = -1e30f, m2 = -1e30f;
#pragma unroll
      for (int mm = 0; mm < 8; ++mm) {
        int m = w*8 + mm;
        float a = *(const float*)(Lp + L_ALP + (m*64 + s)*4);
        float c = *(const float*)(Lp + L_CLP + (m*64 + s)*4);
        m1 = fmaxf(m1, a + c); m2 = fmaxf(m2, a);
      }
      *(float*)(Lp + L_LM1 + (w*64 + s)*4) = m1;
      *(float*)(Lp + L_LM2 + (w*64 + s)*4) = m2;
      __syncthreads();
      g1 = fmaxf(fmaxf(*(const float*)(Lp + L_LM1 + s*4),
                       *(const float*)(Lp + L_LM1 + (64 + s)*4)),
                 fmaxf(*(const float*)(Lp + L_LM1 + (128 + s)*4),
                       *(const float*)(Lp + L_LM1 + (192 + s)*4)));
      g2 = fmaxf(fmaxf(*(const float*)(Lp + L_LM2 + s*4),
                       *(const float*)(Lp + L_LM2 + (64 + s)*4)),
                 fmaxf(*(const float*)(Lp + L_LM2 + (128 + s)*4),
                       *(const float*)(Lp + L_LM2 + (192 + s)*4)));
      float s1 = 0.f, s2 = 0.f;
#pragma unroll
      for (int mm = 0; mm < 8; ++mm) {
        int m = w*8 + mm;
        float a = *(const float*)(Lp + L_ALP + (m*64 + s)*4);
        float c = *(const float*)(Lp + L_CLP + (m*64 + s)*4);
        s1 += __expf(a + c - g1); s2 += __expf(a - g2);
      }
      *(float*)(Lp + L_LS1 + (w*64 + s)*4) = s1;
      *(float*)(Lp + L_LS2 + (w*64 + s)*4) = s2;
      __syncthreads();
    }
    if (tid < 64) {
      float s1 = *(const float*)(Lp + L_LS1 + tid*4)
               + *(const float*)(Lp + L_LS1 + (64 + tid)*4)
               + *(const float*)(Lp + L_LS1 + (128 + tid)*4)
               + *(const float*)(Lp + L_LS1 + (192 + tid)*4);
      float s2 = *(const float*)(Lp + L_LS2 + tid*4)
               + *(const float*)(Lp + L_LS2 + (64 + tid)*4)
               + *(const float*)(Lp + L_LS2 + (128 + tid)*4)
               + *(const float*)(Lp + L_LS2 + (192 + tid)*4);
      res += (g1 + __logf(s1)) - (g2 + __logf(s2));
    }
    if (t == 15) break;
    __syncthreads();   // CLP/ALP reads done before encoder overwrites staging

    // ---- encoder: 5-phase pipeline ----
    f32x4 acE[4];
#pragma unroll
    for (int st = 0; st < 4; ++st) acE[st] = (f32x4){0.f,0.f,0.f,0.f};
#pragma unroll 1
    for (int p = 0; p <= 4; ++p) {
      if (p < 4) {
        const u16* aep = ws + O_E1W + (p*64 + w*16 + li)*32 + 8*g;
        uint4 ae = *(const uint4*)aep;
        float4 bb = *(const float4*)(b1e + p*64 + w*16 + 4*g);
        char* H1b = Lp + ((p & 1) ? L_H1B : L_H1A);
#pragma unroll
        for (int st = 0; st < 4; ++st) {
          int s = st*16 + li;
          uint4 b0 = *(const uint4*)(Lp + L_XP + s*64 + ((16*g) ^ ((s & 3) << 4)));
          f32x4 ah = (f32x4){0.f,0.f,0.f,0.f};
          ah = MF(ae, b0, ah);
          float v0 = fmaxf(ah[0] + bb.x, 0.f), v1 = fmaxf(ah[1] + bb.y, 0.f);
          float v2 = fmaxf(ah[2] + bb.z, 0.f), v3 = fmaxf(ah[3] + bb.w, 0.f);
          *(u32*)(H1b + s*128 + ((32*w + 8*g) ^ sw))     = pk2(v0, v1);
          *(u32*)(H1b + s*128 + ((32*w + 8*g + 4) ^ sw)) = pk2(v2, v3);
        }
      }
      if (p > 0) {
        int q = p - 1;
        const u16* c0p = ws + O_E2W + (w*16 + li)*256 + q*64 + 8*g;
        uint4 c0 = *(const uint4*)c0p, c1 = *(const uint4*)(c0p + 32);
        const char* H1r = Lp + ((q & 1) ? L_H1B : L_H1A);
#pragma unroll
        for (int st = 0; st < 4; ++st) {
          int s = st*16 + li;
          uint4 b0 = *(const uint4*)(H1r + s*128 + ((16*g) ^ sw));
          uint4 b1 = *(const uint4*)(H1r + s*128 + ((64 + 16*g) ^ sw));
          acE[st] = MF(c0, b0, acE[st]); acE[st] = MF(c1, b1, acE[st]);
        }
      }
      if (p == 4) { // ENC epilogue: f32 [s][d], 32B-granule XOR swizzle
        float4 be = *(const float4*)(b2e + w*16 + 4*g);
        const float bev[4] = {be.x, be.y, be.z, be.w};
#pragma unroll
        for (int st = 0; st < 4; ++st) {
          int s = st*16 + li;
#pragma unroll
          for (int r = 0; r < 4; ++r) {
            int d = w*16 + 4*g + r;
            *(float*)(Lp + L_ENC + s*256 + ((((d >> 3) ^ e3)) << 5) + ((d & 7) << 2))
                = acE[st][r] + bev[r];
          }
        }
      }
      __syncthreads();
    }

    // ---- update: per-d MFMA Y_d = core_d * tmp, then acc += enc[d]*Y_d ----
    // wave w owns j rows [w*16, w*16+16); no cross-wave reduction.
    f32x4 acc[4];
#pragma unroll
    for (int st = 0; st < 4; ++st) acc[st] = (f32x4){0.f,0.f,0.f,0.f};
    const u16* AJ = ws + O_CORT + (size_t)t*CORT_STEP + (size_t)(w*16 + li)*64 + 8*g;
    uint4 Ac0 = *(const uint4*)(AJ);
    uint4 Ac1 = *(const uint4*)(AJ + 32);
#pragma unroll 1
    for (int dg = 0; dg < 16; ++dg) {
      f32x4 E[4];
#pragma unroll
      for (int st = 0; st < 4; ++st)
        E[st] = *(const f32x4*)(Lp + L_ENC + (st*16 + li)*256 +
                                (((dg >> 1) ^ e3) << 5) + ((dg & 1) << 4));
#pragma unroll
      for (int dd = 0; dd < 4; ++dd) {
        uint4 An0 = Ac0, An1 = Ac1;
        if (dd < 3 || dg < 15) {
          const u16* ap = AJ + (size_t)(dg*4 + dd + 1)*4096;
          An0 = *(const uint4*)(ap);
          An1 = *(const uint4*)(ap + 32);
        }
        __builtin_amdgcn_s_setprio(1);
#pragma unroll
        for (int st = 0; st < 4; ++st) {
          f32x4 y = (f32x4){0.f,0.f,0.f,0.f};
          y = MF(Ac0, Bq0[st], y);
          y = MF(Ac1, Bq1[st], y);
          float e = E[st][dd];
          acc[st][0] += e * y[0]; acc[st][1] += e * y[1];
          acc[st][2] += e * y[2]; acc[st][3] += e * y[3];
        }
        __builtin_amdgcn_s_setprio(0);
        Ac0 = An0; Ac1 = An1;
      }
    }
    // epilogue: norm + write tmp_{t+1} into the single TMP buffer
#pragma unroll
    for (int st = 0; st < 4; ++st) {
      int s = st*16 + li;
      nrm += acc[st][0]*acc[st][0] + acc[st][1]*acc[st][1]
           + acc[st][2]*acc[st][2] + acc[st][3]*acc[st][3];
      uint2 pv;
      pv.x = pk2(acc[st][0], acc[st][1]);
      pv.y = pk2(acc[st][2], acc[st][3]);
      *(uint2*)(Lp + L_TMP + s*128 + ((32*w + 8*g) ^ sw)) = pv;
    }
    __syncthreads();
  } // t loop

  if (tid < 64) out[n0 + tid] = res;

  __syncthreads();
  *(float*)(Lp + L_H1A + tid*4) = nrm;
  __syncthreads();
  if (tid < 64) {
    float v = *(const float*)(Lp + L_H1A + tid*4)
            + *(const float*)(Lp + L_H1A + (tid + 64)*4)
            + *(const float*)(Lp + L_H1A + (tid + 128)*4)
            + *(const float*)(Lp + L_H1A + (tid + 192)*4);
#pragma unroll
    for (int off = 32; off > 0; off >>= 1) v += __shfl_down(v, off);
    if (tid == 0) atomicAdd(out + NSAMP, v);
  }
}

extern "C" void kernel_launch(void* const* d_in, const int* in_sizes, int n_in,
                              void* d_out, int out_size, void* d_ws, size_t ws_size,
                              hipStream_t stream) {
  const float* X      = (const float*)d_in[0];
  const float* init_w = (const float*)d_in[1];
  const float* cores  = (const float*)d_in[2];
  const float* e1w    = (const float*)d_in[3];
  const float* b1e    = (const float*)d_in[4];
  const float* e2w    = (const float*)d_in[5];
  const float* b2e    = (const float*)d_in[6];
  const float* nw1    = (const float*)d_in[7];
  const float* b1n    = (const float*)d_in[8];
  const float* nw2    = (const float*)d_in[9];
  const float* b2n    = (const float*)d_in[10];
  const float* muw    = (const float*)d_in[11];
  const float* mub    = (const float*)d_in[12];
  const float* sgw    = (const float*)d_in[13];
  const float* sgb    = (const float*)d_in[14];
  const float* alw    = (const float*)d_in[15];
  const float* alb    = (const float*)d_in[16];
  float* out = (float*)d_out;
  u16*   ws  = (u16*)d_ws;

  prep_w<<<64, 256, 0, stream>>>(nw1, nw2, muw, sgw, alw, e1w, e2w, ws, out);
  prep_core<<<960, 256, 0, stream>>>(cores, ws);
  fused<<<NSAMP/64, 256, 0, stream>>>(X, init_w, b1e, b2e, b1n, b2n,
                                      mub, sgb, alb, ws, out);
}